// Round 2
// baseline (20008.759 us; speedup 1.0000x reference)
//
#include <hip/hip_runtime.h>
#include <cstdint>
#include <cstddef>

#define SEQ   8192
#define HD    2048
#define IND   16
#define NBLK  256   // one block per CU; each owns 8 hidden units
#define NTHR  512   // 8 waves; wave w owns unit b*8+w (4 gate rows)
#define NUNIT 2048  // u32 slots per parity: lo16 = fp16 h, hi16 = tag (t+1<=8192)
#define NXCD  8

// Poll gate: data for step t+1 cannot be globally visible before OUR OWN
// step-t publish (+min store->load flight), because every peer block also
// waits on our slots. 14 refclk ticks @100MHz ~= 140ns ~= 340 GPU cycles,
// below the minimum LLC store->load visibility latency -> provably adds no
// latency (even for straggler blocks), only removes wasted poll rounds.
// Constant offset from own publish -> no feedback ratchet possible.
#define GATE_TICKS 14ull

typedef _Float16 h2  __attribute__((ext_vector_type(2)));
typedef unsigned u32x4 __attribute__((ext_vector_type(4)));

union paircvt { h2 v; unsigned u; };
union hcvt { _Float16 f; unsigned short u; };

__device__ __forceinline__ float fdot2f(h2 a, h2 b, float c) {
#if defined(__has_builtin)
#if __has_builtin(__builtin_amdgcn_fdot2)
    return __builtin_amdgcn_fdot2(a, b, c, false);
#else
    return c + (float)a.x * (float)b.x + (float)a.y * (float)b.y;
#endif
#else
    return c + (float)a.x * (float)b.x + (float)a.y * (float)b.y;
#endif
}

__device__ __forceinline__ float sigmoid_f(float x) {
    return 1.f / (1.f + __expf(-x));
}
__device__ __forceinline__ float tanh_f(float x) {
    float e = __expf(2.f * x);
    return 1.f - 2.f / (e + 1.f);
}

__device__ __forceinline__ unsigned my_xcd() {
    unsigned x;
    asm volatile("s_getreg_b32 %0, hwreg(HW_REG_XCC_ID, 0, 4)" : "=s"(x));
    return x & (NXCD - 1);
}

// Persistent LSTM, round 11: shrink the serial compute tail.
// R10 landed at ~4430 cy/step (MfmaUtil 0, HBM 2.1% -> still sync-latency
// bound). Tail was structural: 2 units/wave -> 128 fdot2/lane + 7-deep
// shuffle chain + 4 gate-broadcast shuffles. This round: 8 waves, ONE unit
// per wave:
//  (1) 64 fdot2/lane (half), 2 waves/SIMD interleave dependent chains.
//  (2) plain 6-stage xor tree on 4 accs: every lane ends with ALL 4 gate
//      sums -> gate broadcast shuffles deleted, gate math lane-local.
//  (3) xp injected free: lane r (r<4) inits p[r]=xp before the dot loop.
//  (4) u32 message/unit (hi16=tag, lo16=fp16 h): poll is ONE dwordx4 per
//      thread (512x16B = full 8KB parity region), shorter round.
// LDS swizzle pattern per store instruction is bit-identical to R10
// (p = 128w + 2L), <=2-way = free. Publish still one predicated store
// (lanes 0..7 -> 8 XCD replicas). Gate kept at 14 ticks.
__global__ __launch_bounds__(NTHR, 1) void lstm_persist(
    const float* __restrict__ sa,    // [SEQ, IND]
    const float* __restrict__ W_ih,  // [4*HD, IND]
    const float* __restrict__ W_hh,  // [4*HD, HD]
    const float* __restrict__ b_ih,  // [4*HD]
    const float* __restrict__ b_hh,  // [4*HD]
    unsigned* __restrict__ hrep,     // [NXCD][2][NUNIT] u32 replicas
    _Float16* __restrict__ hs16)     // [SEQ, HD] h history (fp16)
{
    const int b   = blockIdx.x;
    const int tid = threadIdx.x;
    const int w   = tid >> 6;        // wave 0..7
    const int L   = tid & 63;        // lane
    const unsigned xcd = my_xcd();

    __shared__ h2 hh2[16 * 64];      // h_t pairs, XOR-swizzled [k][row^2k]

    const int unit = b * 8 + w;      // this wave's hidden unit

    // ---- one-time: W_hh fragment -> registers (fp16 pairs) ----
    // 4 gate rows r, lane L owns cols [32L, 32L+32)
    h2 wreg[4][16];
#pragma unroll
    for (int r = 0; r < 4; ++r) {
        const int row = r * HD + unit;
        const float4* Wr = (const float4*)(W_hh + (size_t)row * HD + L * 32);
#pragma unroll
        for (int q = 0; q < 8; ++q) {
            float4 f = Wr[q];
            h2 lo; lo.x = (_Float16)f.x; lo.y = (_Float16)f.y;
            h2 hi; hi.x = (_Float16)f.z; hi.y = (_Float16)f.w;
            wreg[r][2 * q]     = lo;
            wreg[r][2 * q + 1] = hi;
        }
    }
    // W_ih row + bias for gate row (L&3); only lanes 0..3's xp is consumed
    const int rowL = (L & 3) * HD + unit;
    float wih[IND];
    {
        const float4* Wi = (const float4*)(W_ih + (size_t)rowL * IND);
#pragma unroll
        for (int q = 0; q < 4; ++q) {
            float4 f = Wi[q];
            wih[4 * q]     = f.x;
            wih[4 * q + 1] = f.y;
            wih[4 * q + 2] = f.z;
            wih[4 * q + 3] = f.w;
        }
    }
    const float bias = b_ih[rowL] + b_hh[rowL];

    // x_t prefetch registers (depth 1)
    float sat[IND];
    {
        const float4* s4 = (const float4*)(sa);
#pragma unroll
        for (int q = 0; q < 4; ++q) {
            float4 f = s4[q];
            sat[4 * q]     = f.x;
            sat[4 * q + 1] = f.y;
            sat[4 * q + 2] = f.z;
            sat[4 * q + 3] = f.w;
        }
    }

    float c = 0.f;                   // cell state (redundant across lanes)
    unsigned long long pubclk = 0;

    for (unsigned t = 0; t < SEQ; ++t) {
        // ---- xp from prefetched x_t (no serial load stall) ----
        float xp = bias;
#pragma unroll
        for (int k = 0; k < IND; ++k) xp += sat[k] * wih[k];

        // ---- issue x_{t+1} prefetch; retires under this step's wait ----
        if (t + 1 < SEQ) {
            const float4* s4 = (const float4*)(sa + (size_t)(t + 1) * IND);
#pragma unroll
            for (int q = 0; q < 4; ++q) {
                float4 f = s4[q];
                sat[4 * q]     = f.x;
                sat[4 * q + 1] = f.y;
                sat[4 * q + 2] = f.z;
                sat[4 * q + 3] = f.w;
            }
        }

        // ---- clock gate: no LLC polls before own-publish + min flight ----
        if (t) {
            unsigned long long now;
            do {
                now = __builtin_amdgcn_s_memrealtime();
            } while (now - pubclk < GATE_TICKS);
        }

        // ---- poll own-XCD replica: ONE dwordx4 = units [4*tid, 4*tid+4) ----
        const unsigned pin = t & 1;
        const uint32_t* pp =
            (const uint32_t*)hrep + ((size_t)xcd * 2 + pin) * NUNIT + 4 * tid;
        u32x4 m;
        int tries = 0;
        for (;;) {
            asm volatile(
                "global_load_dwordx4 %0, %1, off sc1\n\t"
                "s_waitcnt vmcnt(0)"
                : "=v"(m)
                : "v"(pp) : "memory");
            bool ok = ((m.x >> 16) == t) & ((m.y >> 16) == t) &
                      ((m.z >> 16) == t) & ((m.w >> 16) == t);
            if (ok) break;
            if (++tries > 2) __builtin_amdgcn_s_sleep(1);
        }

        // ---- build 2 h-pairs, stage into swizzled LDS (<=2-way = free) ----
        {
            paircvt cv;
            const int pa = 2 * tid, pb = 2 * tid + 1;
            cv.u = (m.y << 16) | (m.x & 0xffffu);
            hh2[(pa & 15) * 64 + (((pa >> 4) ^ (2 * (pa & 15))) & 63)] = cv.v;
            cv.u = (m.w << 16) | (m.z & 0xffffu);
            hh2[(pb & 15) * 64 + (((pb >> 4) ^ (2 * (pb & 15))) & 63)] = cv.v;
        }
        __syncthreads();

        // ---- read this lane's 16 pairs (cols [32L, 32L+32)) ----
        h2 hv[16];
#pragma unroll
        for (int k = 0; k < 16; ++k)
            hv[k] = hh2[k * 64 + ((L ^ (2 * k)) & 63)];

        // ---- 4 gate rows x 32 cols of dot product per lane ----
        // xp injected at tree leaf: lane r (r<4) seeds p[r] with its row's xp
        float p0 = (L == 0) ? xp : 0.f;
        float p1 = (L == 1) ? xp : 0.f;
        float p2 = (L == 2) ? xp : 0.f;
        float p3 = (L == 3) ? xp : 0.f;
#pragma unroll
        for (int k = 0; k < 16; ++k) {
            p0 = fdot2f(wreg[0][k], hv[k], p0);
            p1 = fdot2f(wreg[1][k], hv[k], p1);
            p2 = fdot2f(wreg[2][k], hv[k], p2);
            p3 = fdot2f(wreg[3][k], hv[k], p3);
        }

        // ---- full xor tree: every lane ends with all 4 gate sums ----
#pragma unroll
        for (int d = 1; d < 64; d <<= 1) {
            p0 += __shfl_xor(p0, d, 64);
            p1 += __shfl_xor(p1, d, 64);
            p2 += __shfl_xor(p2, d, 64);
            p3 += __shfl_xor(p3, d, 64);
        }

        // ---- gates: fully lane-local (PyTorch order i,f,g,o) ----
        float ii = sigmoid_f(p0);
        float ff = sigmoid_f(p1);
        float g  = tanh_f(p2);
        float oo = sigmoid_f(p3);
        c = ff * c + ii * g;
        float h = oo * tanh_f(c);   // identical on all 64 lanes

        // ---- publish: lanes 0..7 each store one replica (1 issue) ----
        {
            hcvt hc; hc.f = (_Float16)h;
            const unsigned msg = ((t + 1) << 16) | (unsigned)hc.u;
            const unsigned pout = (t + 1) & 1;
            if (L < 8)
                __hip_atomic_store(
                    &hrep[((size_t)L * 2 + pout) * NUNIT + unit], msg,
                    __ATOMIC_RELAXED, __HIP_MEMORY_SCOPE_AGENT);
            // non-critical history write after the critical publish
            if (L == 8)
                hs16[(size_t)t * HD + unit] = (_Float16)h;
        }
        pubclk = __builtin_amdgcn_s_memrealtime();
    }
}

// Output projection: out[t,0:3] = hs[t]·W_uvw^T + b_uvw,
//                    out[t,3:6] = hs[t]·W_pqr^T + b_pqr
__global__ __launch_bounds__(256) void out_proj_kernel(
    const _Float16* __restrict__ hs16,
    const float* __restrict__ W_uvw, const float* __restrict__ b_uvw,
    const float* __restrict__ W_pqr, const float* __restrict__ b_pqr,
    float* __restrict__ out)
{
    __shared__ float Ws[6 * HD];
    const int tid = threadIdx.x;
    for (int i = tid; i < 3 * HD; i += 256) Ws[i] = W_uvw[i];
    for (int i = tid; i < 3 * HD; i += 256) Ws[3 * HD + i] = W_pqr[i];
    __syncthreads();

    const int w = tid >> 6, L = tid & 63;
#pragma unroll
    for (int r = 0; r < 4; ++r) {
        const int t = blockIdx.x * 16 + w * 4 + r;
        const _Float16* hrow = hs16 + (size_t)t * HD;
        float acc[6] = {0.f, 0.f, 0.f, 0.f, 0.f, 0.f};
        for (int cidx = L; cidx < HD; cidx += 64) {
            float hval = (float)hrow[cidx];
#pragma unroll
            for (int j = 0; j < 6; ++j) acc[j] += hval * Ws[j * HD + cidx];
        }
#pragma unroll
        for (int j = 0; j < 6; ++j) {
#pragma unroll
            for (int d = 1; d < 64; d <<= 1)
                acc[j] += __shfl_xor(acc[j], d, 64);
        }
        if (L == 0) {
#pragma unroll
            for (int j = 0; j < 6; ++j)
                out[(size_t)t * 6 + j] =
                    acc[j] + (j < 3 ? b_uvw[j] : b_pqr[j - 3]);
        }
    }
}

extern "C" void kernel_launch(void* const* d_in, const int* in_sizes, int n_in,
                              void* d_out, int out_size, void* d_ws, size_t ws_size,
                              hipStream_t stream) {
    (void)in_sizes; (void)n_in; (void)out_size; (void)ws_size;

    const float* sa    = (const float*)d_in[0];
    const float* W_ih  = (const float*)d_in[1];
    const float* W_hh  = (const float*)d_in[2];
    const float* b_ih  = (const float*)d_in[3];
    const float* b_hh  = (const float*)d_in[4];
    const float* W_uvw = (const float*)d_in[5];
    const float* b_uvw = (const float*)d_in[6];
    const float* W_pqr = (const float*)d_in[7];
    const float* b_pqr = (const float*)d_in[8];
    float* out = (float*)d_out;

    // workspace: [hs16: 32 MB][hrep: NXCD*2*NUNIT*4 = 128 KB]
    char* ws = (char*)d_ws;
    _Float16* hs16 = (_Float16*)ws;
    unsigned* hrep = (unsigned*)(ws + (size_t)SEQ * HD * 2);

    // zero replicas: tag 0 == "h_0 = 0 is ready" in every copy
    hipMemsetAsync(hrep, 0, (size_t)NXCD * 2 * NUNIT * 4, stream);

    hipLaunchKernelGGL(lstm_persist, dim3(NBLK), dim3(NTHR), 0, stream,
                       sa, W_ih, W_hh, b_ih, b_hh, hrep, hs16);
    hipLaunchKernelGGL(out_proj_kernel, dim3(SEQ / 16), dim3(256), 0, stream,
                       hs16, W_uvw, b_uvw, W_pqr, b_pqr, out);
}

// Round 3
// 16234.914 us; speedup vs baseline: 1.2325x; 1.2325x over previous
//
#include <hip/hip_runtime.h>
#include <cstdint>
#include <cstddef>

#define SEQ   8192
#define HD    2048
#define IND   16
#define NBLK  256   // one block per CU; each owns 8 hidden units
#define NTHR  256   // 4 waves; wave w owns units {b*8+2w, b*8+2w+1} = 8 rows
#define NSLOT 1024  // u64 slots per parity: lo32 = 2xfp16 h-pair, hi32 = tag
#define NXCD  8

// Poll gate: data for step t+1 cannot be globally visible before OUR OWN
// step-t publish (+min store->load flight), because every peer block also
// waits on our slots. 14 refclk ticks @100MHz ~= 140ns ~= 340 GPU cycles,
// below the minimum LLC store->load visibility latency -> provably adds no
// latency (even for straggler blocks), only removes wasted poll rounds.
#define GATE_TICKS 14ull

typedef _Float16 h2  __attribute__((ext_vector_type(2)));
typedef unsigned u32x4 __attribute__((ext_vector_type(4)));

union paircvt { h2 v; unsigned u; };

__device__ __forceinline__ float fdot2f(h2 a, h2 b, float c) {
#if defined(__has_builtin)
#if __has_builtin(__builtin_amdgcn_fdot2)
    return __builtin_amdgcn_fdot2(a, b, c, false);
#else
    return c + (float)a.x * (float)b.x + (float)a.y * (float)b.y;
#endif
#else
    return c + (float)a.x * (float)b.x + (float)a.y * (float)b.y;
#endif
}

__device__ __forceinline__ float sigmoid_f(float x) {
    return 1.f / (1.f + __expf(-x));
}
__device__ __forceinline__ float tanh_f(float x) {
    float e = __expf(2.f * x);
    return 1.f - 2.f / (e + 1.f);
}

__device__ __forceinline__ unsigned my_xcd() {
    unsigned x;
    asm volatile("s_getreg_b32 %0, hwreg(HW_REG_XCC_ID, 0, 4)" : "=s"(x));
    return x & (NXCD - 1);
}

// ---- VALU cross-lane primitives (replace DS-pipe shuffles) ----
// xor-1 / xor-2 are exact DPP quad_perm patterns: ~8cy VALU vs ~40cy DS.
__device__ __forceinline__ float dpp_xor1(float x) {
    int i = __builtin_bit_cast(int, x);
    // quad_perm [1,0,3,2] = 0xB1 : lane L reads L^1
    int r = __builtin_amdgcn_mov_dpp(i, 0xB1, 0xf, 0xf, false);
    return __builtin_bit_cast(float, r);
}
__device__ __forceinline__ float dpp_xor2(float x) {
    int i = __builtin_bit_cast(int, x);
    // quad_perm [2,3,0,1] = 0x4E : lane L reads L^2
    int r = __builtin_amdgcn_mov_dpp(i, 0x4E, 0xf, 0xf, false);
    return __builtin_bit_cast(float, r);
}
// gfx950 permlane swaps: copy+swap+add = xor-16 / xor-32 butterfly stage,
// bit-identical result (commutative add), VALU-pipe instead of DS-pipe.
__device__ __forceinline__ float xor16_add(float x) {
    float a = x, b = x;
    asm volatile("v_permlane16_swap_b32 %0, %1" : "+v"(a), "+v"(b));
    return a + b;
}
__device__ __forceinline__ float xor32_add(float x) {
    float a = x, b = x;
    asm volatile("v_permlane32_swap_b32 %0, %1" : "+v"(a), "+v"(b));
    return a + b;
}

// Persistent LSTM, round 12: revert to R10 structure (R11's 8-wave split
// regressed: 2x store messages -> WRITE_SIZE doubled, 3.4x DS reduce ops,
// 8-wave barrier coupling). On top of R10, three serial-latency trims,
// compute arithmetic bit-identical:
//  (1) reduce tree: xor1/xor2 via DPP quad_perm, xor16/xor32 via
//      v_permlane{16,32}_swap_b32 -> 4 of 6 dependent DS hops become VALU
//      (~120-150cy off the post-poll critical path, less DS contention).
//  (2) sat (x_{t+1}) prefetch moved AFTER poll success: its loads no
//      longer sit inside the poll's s_waitcnt vmcnt(0), so an occasional
//      L2/HBM miss can't land on the discovery path. ~1000cy slack before
//      next xp use remains.
//  (3) LDS swizzle write/read addresses hoisted out of the t-loop
//      (loop-invariant); hs16 history store moved to lane 8 so publishing
//      lanes 0..7 are unburdened.
// Gate (14 ticks), poll scheme, u64 message format, lane-spread publish:
// unchanged from R10.
__global__ __launch_bounds__(NTHR, 1) void lstm_persist(
    const float* __restrict__ sa,    // [SEQ, IND]
    const float* __restrict__ W_ih,  // [4*HD, IND]
    const float* __restrict__ W_hh,  // [4*HD, HD]
    const float* __restrict__ b_ih,  // [4*HD]
    const float* __restrict__ b_hh,  // [4*HD]
    unsigned long long* __restrict__ hrep,  // [NXCD][2][NSLOT] replicas
    _Float16* __restrict__ hs16)     // [SEQ, HD] h history (fp16)
{
    const int b   = blockIdx.x;
    const int tid = threadIdx.x;
    const int w   = tid >> 6;        // wave 0..3
    const int L   = tid & 63;        // lane
    const unsigned xcd = my_xcd();

    __shared__ h2 hh2[16 * 64];      // h_t pairs, XOR-swizzled [k][row^2k]

    const int ubase = b * 8 + 2 * w; // first of this wave's 2 units

    // ---- one-time: W_hh fragment -> registers (fp16 pairs) ----
    // 8 rows (r: gate=r&3, unit=r>>2), lane L owns cols [32L, 32L+32)
    h2 wreg[8][16];
#pragma unroll
    for (int r = 0; r < 8; ++r) {
        const int row = (r & 3) * HD + ubase + (r >> 2);
        const float4* Wr = (const float4*)(W_hh + (size_t)row * HD + L * 32);
#pragma unroll
        for (int q = 0; q < 8; ++q) {
            float4 f = Wr[q];
            h2 lo; lo.x = (_Float16)f.x; lo.y = (_Float16)f.y;
            h2 hi; hi.x = (_Float16)f.z; hi.y = (_Float16)f.w;
            wreg[r][2 * q]     = lo;
            wreg[r][2 * q + 1] = hi;
        }
    }
    // W_ih row + bias for the row this lane ends up holding (r = L&7)
    const int rowL = (L & 3) * HD + ubase + ((L >> 2) & 1);
    float wih[IND];
    {
        const float4* Wi = (const float4*)(W_ih + (size_t)rowL * IND);
#pragma unroll
        for (int q = 0; q < 4; ++q) {
            float4 f = Wi[q];
            wih[4 * q]     = f.x;
            wih[4 * q + 1] = f.y;
            wih[4 * q + 2] = f.z;
            wih[4 * q + 3] = f.w;
        }
    }
    const float bias = b_ih[rowL] + b_hh[rowL];

    // ---- hoisted LDS addresses (loop-invariant swizzle math) ----
    h2* wp0; h2* wp1; h2* wp2; h2* wp3;
    {
        const int pa = 2 * tid, pb = 2 * tid + 1;
        const int pc = 512 + 2 * tid, pd = 513 + 2 * tid;
        wp0 = &hh2[(pa & 15) * 64 + (((pa >> 4) ^ (2 * (pa & 15))) & 63)];
        wp1 = &hh2[(pb & 15) * 64 + (((pb >> 4) ^ (2 * (pb & 15))) & 63)];
        wp2 = &hh2[(pc & 15) * 64 + (((pc >> 4) ^ (2 * (pc & 15))) & 63)];
        wp3 = &hh2[(pd & 15) * 64 + (((pd >> 4) ^ (2 * (pd & 15))) & 63)];
    }
    const h2* rp[16];
#pragma unroll
    for (int k = 0; k < 16; ++k)
        rp[k] = &hh2[k * 64 + ((L ^ (2 * k)) & 63)];

    // x_t prefetch registers (depth 1)
    float sat[IND];
    {
        const float4* s4 = (const float4*)(sa);
#pragma unroll
        for (int q = 0; q < 4; ++q) {
            float4 f = s4[q];
            sat[4 * q]     = f.x;
            sat[4 * q + 1] = f.y;
            sat[4 * q + 2] = f.z;
            sat[4 * q + 3] = f.w;
        }
    }

    // cell state: lanes with (L&4)==0 hold c of unit0, (L&4)==4 -> unit1
    float c = 0.f;
    unsigned long long pubclk = 0;

    for (unsigned t = 0; t < SEQ; ++t) {
        // ---- xp from prefetched x_t (no serial load stall) ----
        float xp = bias;
#pragma unroll
        for (int k = 0; k < IND; ++k) xp += sat[k] * wih[k];

        // ---- clock gate: no LLC polls before own-publish + min flight ----
        if (t) {
            unsigned long long now;
            do {
                now = __builtin_amdgcn_s_memrealtime();
            } while (now - pubclk < GATE_TICKS);
        }

        // ---- poll own-XCD replica (sc1: memory-side, never stale) ----
        const unsigned pin = t & 1;
        const uint32_t* base =
            (const uint32_t*)(hrep + ((size_t)xcd * 2 + pin) * NSLOT);
        const uint32_t* pp0 = base + 4 * tid;
        const uint32_t* pp1 = base + 1024 + 4 * tid;
        u32x4 m0, m1;
        int tries = 0;
        for (;;) {
            asm volatile(
                "global_load_dwordx4 %0, %2, off sc1\n\t"
                "global_load_dwordx4 %1, %3, off sc1\n\t"
                "s_waitcnt vmcnt(0)"
                : "=v"(m0), "=v"(m1)
                : "v"(pp0), "v"(pp1) : "memory");
            bool ok = (m0.y == t) & (m0.w == t) & (m1.y == t) & (m1.w == t);
            if (ok) break;
            if (++tries > 2) __builtin_amdgcn_s_sleep(1);
        }

        // ---- stage 4 pairs into swizzled LDS (<=2-way = free) ----
        {
            paircvt cv;
            cv.u = m0.x; *wp0 = cv.v;
            cv.u = m0.z; *wp1 = cv.v;
            cv.u = m1.x; *wp2 = cv.v;
            cv.u = m1.z; *wp3 = cv.v;
        }

        // ---- issue x_{t+1} prefetch: OUTSIDE the poll's vmcnt scope,
        //      retires under dots/reduce (~1000cy slack) ----
        if (t + 1 < SEQ) {
            const float4* s4 = (const float4*)(sa + (size_t)(t + 1) * IND);
#pragma unroll
            for (int q = 0; q < 4; ++q) {
                float4 f = s4[q];
                sat[4 * q]     = f.x;
                sat[4 * q + 1] = f.y;
                sat[4 * q + 2] = f.z;
                sat[4 * q + 3] = f.w;
            }
        }
        __syncthreads();

        // ---- read this lane's 16 pairs (cols [32L, 32L+32)) ----
        h2 hv[16];
#pragma unroll
        for (int k = 0; k < 16; ++k)
            hv[k] = *rp[k];

        // ---- 8 rows x 32 cols of dot product per lane ----
        float p[8] = {0.f, 0.f, 0.f, 0.f, 0.f, 0.f, 0.f, 0.f};
#pragma unroll
        for (int r = 0; r < 8; ++r)
#pragma unroll
            for (int k = 0; k < 16; ++k)
                p[r] = fdot2f(wreg[r][k], hv[k], p[r]);

        // ---- merge-reduce: lane L ends with full sum of row (L&7) ----
        // xor1/xor2 stages on DPP (VALU), xor4/8 on DS, xor16/32 on
        // permlane swaps (VALU). Bit-identical arithmetic to R10.
        const bool h1 = (L & 1), h2b = (L & 2), h4 = (L & 4);
        float v0, v1, v2, v3;
        {
            float k0 = h1 ? p[1] : p[0], s0 = h1 ? p[0] : p[1];
            v0 = k0 + dpp_xor1(s0);
            float k1 = h1 ? p[3] : p[2], s1 = h1 ? p[2] : p[3];
            v1 = k1 + dpp_xor1(s1);
            float k2 = h1 ? p[5] : p[4], s2 = h1 ? p[4] : p[5];
            v2 = k2 + dpp_xor1(s2);
            float k3 = h1 ? p[7] : p[6], s3 = h1 ? p[6] : p[7];
            v3 = k3 + dpp_xor1(s3);
        }
        float w0, w1;
        {
            float k0 = h2b ? v1 : v0, s0 = h2b ? v0 : v1;
            w0 = k0 + dpp_xor2(s0);
            float k1 = h2b ? v3 : v2, s1 = h2b ? v2 : v3;
            w1 = k1 + dpp_xor2(s1);
        }
        float tot;
        {
            float k0 = h4 ? w1 : w0, s0 = h4 ? w0 : w1;
            tot = k0 + __shfl_xor(s0, 4, 64);
        }
        tot += __shfl_xor(tot, 8, 64);
        tot = xor16_add(tot);
        tot = xor32_add(tot);
        tot += xp;

        // ---- gates: all intra-wave (width-8 shuffles) ----
        const int ub4 = L & 4;   // 0 -> unit0 rows 0..3, 4 -> unit1 rows 4..7
        float gi = __shfl(tot, ub4 + 0, 8);
        float gf = __shfl(tot, ub4 + 1, 8);
        float gg = __shfl(tot, ub4 + 2, 8);
        float go = __shfl(tot, ub4 + 3, 8);
        float ii = sigmoid_f(gi);
        float ff = sigmoid_f(gf);
        float g  = tanh_f(gg);
        float oo = sigmoid_f(go);
        c = ff * c + ii * g;
        float h = oo * tanh_f(c);
        float hO = __shfl_xor(h, 4, 64);   // lane0: unit1's h (from lane4)

        // ---- publish: lanes 0..7 each store one replica (1 issue) ----
        {
            paircvt pk;
            pk.v.x = (_Float16)h;    // unit ubase   (valid on sublane 0)
            pk.v.y = (_Float16)hO;   // unit ubase+1
            // broadcast sublane-0's packed pair to the whole wave
            unsigned pku = __shfl(pk.u, 0, 8);
            const unsigned pout = (t + 1) & 1;
            const size_t slot = (size_t)b * 4 + w;
            unsigned long long msg =
                ((unsigned long long)(t + 1) << 32) | (unsigned long long)pku;
            if (L < 8)
                __hip_atomic_store(
                    &hrep[((size_t)L * 2 + pout) * NSLOT + slot], msg,
                    __ATOMIC_RELAXED, __HIP_MEMORY_SCOPE_AGENT);
            // non-critical history write, off the publishing lanes
            if (L == 8)
                ((unsigned*)hs16)[(size_t)t * (HD / 2) + b * 4 + w] = pku;
        }
        pubclk = __builtin_amdgcn_s_memrealtime();
    }
}

// Output projection: out[t,0:3] = hs[t]·W_uvw^T + b_uvw,
//                    out[t,3:6] = hs[t]·W_pqr^T + b_pqr
__global__ __launch_bounds__(256) void out_proj_kernel(
    const _Float16* __restrict__ hs16,
    const float* __restrict__ W_uvw, const float* __restrict__ b_uvw,
    const float* __restrict__ W_pqr, const float* __restrict__ b_pqr,
    float* __restrict__ out)
{
    __shared__ float Ws[6 * HD];
    const int tid = threadIdx.x;
    for (int i = tid; i < 3 * HD; i += 256) Ws[i] = W_uvw[i];
    for (int i = tid; i < 3 * HD; i += 256) Ws[3 * HD + i] = W_pqr[i];
    __syncthreads();

    const int w = tid >> 6, L = tid & 63;
#pragma unroll
    for (int r = 0; r < 4; ++r) {
        const int t = blockIdx.x * 16 + w * 4 + r;
        const _Float16* hrow = hs16 + (size_t)t * HD;
        float acc[6] = {0.f, 0.f, 0.f, 0.f, 0.f, 0.f};
        for (int cidx = L; cidx < HD; cidx += 64) {
            float hval = (float)hrow[cidx];
#pragma unroll
            for (int j = 0; j < 6; ++j) acc[j] += hval * Ws[j * HD + cidx];
        }
#pragma unroll
        for (int j = 0; j < 6; ++j) {
#pragma unroll
            for (int d = 1; d < 64; d <<= 1)
                acc[j] += __shfl_xor(acc[j], d, 64);
        }
        if (L == 0) {
#pragma unroll
            for (int j = 0; j < 6; ++j)
                out[(size_t)t * 6 + j] =
                    acc[j] + (j < 3 ? b_uvw[j] : b_pqr[j - 3]);
        }
    }
}

extern "C" void kernel_launch(void* const* d_in, const int* in_sizes, int n_in,
                              void* d_out, int out_size, void* d_ws, size_t ws_size,
                              hipStream_t stream) {
    (void)in_sizes; (void)n_in; (void)out_size; (void)ws_size;

    const float* sa    = (const float*)d_in[0];
    const float* W_ih  = (const float*)d_in[1];
    const float* W_hh  = (const float*)d_in[2];
    const float* b_ih  = (const float*)d_in[3];
    const float* b_hh  = (const float*)d_in[4];
    const float* W_uvw = (const float*)d_in[5];
    const float* b_uvw = (const float*)d_in[6];
    const float* W_pqr = (const float*)d_in[7];
    const float* b_pqr = (const float*)d_in[8];
    float* out = (float*)d_out;

    // workspace: [hs16: 32 MB][hrep: NXCD*2*NSLOT*8 = 128 KB]
    char* ws = (char*)d_ws;
    _Float16* hs16 = (_Float16*)ws;
    unsigned long long* hrep =
        (unsigned long long*)(ws + (size_t)SEQ * HD * 2);

    // zero replicas: tag 0 == "h_0 = 0 is ready" in every copy
    hipMemsetAsync(hrep, 0, (size_t)NXCD * 2 * NSLOT * 8, stream);

    hipLaunchKernelGGL(lstm_persist, dim3(NBLK), dim3(NTHR), 0, stream,
                       sa, W_ih, W_hh, b_ih, b_hh, hrep, hs16);
    hipLaunchKernelGGL(out_proj_kernel, dim3(SEQ / 16), dim3(256), 0, stream,
                       hs16, W_uvw, b_uvw, W_pqr, b_pqr, out);
}

// Round 4
// 14338.174 us; speedup vs baseline: 1.3955x; 1.1323x over previous
//
#include <hip/hip_runtime.h>
#include <cstdint>
#include <cstddef>

#define SEQ   8192
#define HD    2048
#define IND   16
#define NBLK  256   // one block per CU; each owns 8 hidden units
#define NTHR  256   // 4 waves; wave w owns units {b*8+2w, b*8+2w+1} = 8 rows
#define NSLOT 1024  // u64 slots per parity: lo32 = 2xfp16 h-pair, hi32 = tag
#define NXCD  8

// Poll gate: data for step t+1 cannot be globally visible before OUR OWN
// step-t publish (+min store->load flight), because every peer block also
// waits on our slots. 14 refclk ticks @100MHz ~= 140ns ~= 340 GPU cycles,
// below the minimum LLC store->load visibility latency -> provably adds no
// latency (even for straggler blocks), only removes wasted poll rounds.
#define GATE_TICKS 14ull

typedef _Float16 h2  __attribute__((ext_vector_type(2)));
typedef unsigned u32x4 __attribute__((ext_vector_type(4)));

union paircvt { h2 v; unsigned u; };

__device__ __forceinline__ float fdot2f(h2 a, h2 b, float c) {
#if defined(__has_builtin)
#if __has_builtin(__builtin_amdgcn_fdot2)
    return __builtin_amdgcn_fdot2(a, b, c, false);
#else
    return c + (float)a.x * (float)b.x + (float)a.y * (float)b.y;
#endif
#else
    return c + (float)a.x * (float)b.x + (float)a.y * (float)b.y;
#endif
}

__device__ __forceinline__ float sigmoid_f(float x) {
    return 1.f / (1.f + __expf(-x));
}
__device__ __forceinline__ float tanh_f(float x) {
    float e = __expf(2.f * x);
    return 1.f - 2.f / (e + 1.f);
}

__device__ __forceinline__ unsigned my_xcd() {
    unsigned x;
    asm volatile("s_getreg_b32 %0, hwreg(HW_REG_XCC_ID, 0, 4)" : "=s"(x));
    return x & (NXCD - 1);
}

// ---- VALU cross-lane primitives (replace DS-pipe shuffles) ----
// xor-1 / xor-2 are exact DPP quad_perm patterns: ~8cy VALU vs ~40cy DS.
__device__ __forceinline__ float dpp_xor1(float x) {
    int i = __builtin_bit_cast(int, x);
    // quad_perm [1,0,3,2] = 0xB1 : lane L reads L^1
    int r = __builtin_amdgcn_mov_dpp(i, 0xB1, 0xf, 0xf, false);
    return __builtin_bit_cast(float, r);
}
__device__ __forceinline__ float dpp_xor2(float x) {
    int i = __builtin_bit_cast(int, x);
    // quad_perm [2,3,0,1] = 0x4E : lane L reads L^2
    int r = __builtin_amdgcn_mov_dpp(i, 0x4E, 0xf, 0xf, false);
    return __builtin_bit_cast(float, r);
}
// gfx950 permlane swaps: copy+swap+add = xor-16 / xor-32 butterfly stage,
// bit-identical result (commutative add), VALU-pipe instead of DS-pipe.
__device__ __forceinline__ float xor16_add(float x) {
    float a = x, b = x;
    asm volatile("v_permlane16_swap_b32 %0, %1" : "+v"(a), "+v"(b));
    return a + b;
}
__device__ __forceinline__ float xor32_add(float x) {
    float a = x, b = x;
    asm volatile("v_permlane32_swap_b32 %0, %1" : "+v"(a), "+v"(b));
    return a + b;
}

// Persistent LSTM, round 13: R12 regression post-mortem + fix.
// R12 (16.23ms vs R10 15.24ms) had TWO self-inflicted serial stalls:
//  (a) sat prefetch issued between LDS-stage and __syncthreads: the
//      compiler emits s_waitcnt vmcnt(0) before s_barrier, so the 4
//      in-flight x_{t+1} loads drained AT the barrier, on the critical
//      path, every step (~200cy x 8192 ~ 0.8ms -- matches regression).
//      FIX: prefetch back to the pre-gate slot (R10-proven): loads retire
//      under gate+poll's own vmcnt(0); nothing in vmem flight at barrier.
//  (b) publish chain was serialized (shfl_xor -> cvt -> shfl ~80-100cy).
//      FIX: R10's two PARALLEL width-8 broadcasts (hA=shfl(h,0,8),
//      hB=shfl(h,4,8)), pk valid on all lanes; lane 8 writes hs16.
// Kept from R12 (accounted neutral-to-positive after (a)+(b) explain the
// full delta): DPP xor1/xor2 + permlane16/32-swap reduce stages (4 of 6
// dependent DS hops now VALU), hoisted loop-invariant LDS swizzle
// addresses. Gate (14 ticks), poll scheme, u64 messages, lane-spread
// publish: unchanged.
__global__ __launch_bounds__(NTHR, 1) void lstm_persist(
    const float* __restrict__ sa,    // [SEQ, IND]
    const float* __restrict__ W_ih,  // [4*HD, IND]
    const float* __restrict__ W_hh,  // [4*HD, HD]
    const float* __restrict__ b_ih,  // [4*HD]
    const float* __restrict__ b_hh,  // [4*HD]
    unsigned long long* __restrict__ hrep,  // [NXCD][2][NSLOT] replicas
    _Float16* __restrict__ hs16)     // [SEQ, HD] h history (fp16)
{
    const int b   = blockIdx.x;
    const int tid = threadIdx.x;
    const int w   = tid >> 6;        // wave 0..3
    const int L   = tid & 63;        // lane
    const unsigned xcd = my_xcd();

    __shared__ h2 hh2[16 * 64];      // h_t pairs, XOR-swizzled [k][row^2k]

    const int ubase = b * 8 + 2 * w; // first of this wave's 2 units

    // ---- one-time: W_hh fragment -> registers (fp16 pairs) ----
    // 8 rows (r: gate=r&3, unit=r>>2), lane L owns cols [32L, 32L+32)
    h2 wreg[8][16];
#pragma unroll
    for (int r = 0; r < 8; ++r) {
        const int row = (r & 3) * HD + ubase + (r >> 2);
        const float4* Wr = (const float4*)(W_hh + (size_t)row * HD + L * 32);
#pragma unroll
        for (int q = 0; q < 8; ++q) {
            float4 f = Wr[q];
            h2 lo; lo.x = (_Float16)f.x; lo.y = (_Float16)f.y;
            h2 hi; hi.x = (_Float16)f.z; hi.y = (_Float16)f.w;
            wreg[r][2 * q]     = lo;
            wreg[r][2 * q + 1] = hi;
        }
    }
    // W_ih row + bias for the row this lane ends up holding (r = L&7)
    const int rowL = (L & 3) * HD + ubase + ((L >> 2) & 1);
    float wih[IND];
    {
        const float4* Wi = (const float4*)(W_ih + (size_t)rowL * IND);
#pragma unroll
        for (int q = 0; q < 4; ++q) {
            float4 f = Wi[q];
            wih[4 * q]     = f.x;
            wih[4 * q + 1] = f.y;
            wih[4 * q + 2] = f.z;
            wih[4 * q + 3] = f.w;
        }
    }
    const float bias = b_ih[rowL] + b_hh[rowL];

    // ---- hoisted LDS addresses (loop-invariant swizzle math) ----
    h2* wp0; h2* wp1; h2* wp2; h2* wp3;
    {
        const int pa = 2 * tid, pb = 2 * tid + 1;
        const int pc = 512 + 2 * tid, pd = 513 + 2 * tid;
        wp0 = &hh2[(pa & 15) * 64 + (((pa >> 4) ^ (2 * (pa & 15))) & 63)];
        wp1 = &hh2[(pb & 15) * 64 + (((pb >> 4) ^ (2 * (pb & 15))) & 63)];
        wp2 = &hh2[(pc & 15) * 64 + (((pc >> 4) ^ (2 * (pc & 15))) & 63)];
        wp3 = &hh2[(pd & 15) * 64 + (((pd >> 4) ^ (2 * (pd & 15))) & 63)];
    }
    const h2* rp[16];
#pragma unroll
    for (int k = 0; k < 16; ++k)
        rp[k] = &hh2[k * 64 + ((L ^ (2 * k)) & 63)];

    // x_t prefetch registers (depth 1)
    float sat[IND];
    {
        const float4* s4 = (const float4*)(sa);
#pragma unroll
        for (int q = 0; q < 4; ++q) {
            float4 f = s4[q];
            sat[4 * q]     = f.x;
            sat[4 * q + 1] = f.y;
            sat[4 * q + 2] = f.z;
            sat[4 * q + 3] = f.w;
        }
    }

    // cell state: lanes with (L&4)==0 hold c of unit0, (L&4)==4 -> unit1
    float c = 0.f;
    unsigned long long pubclk = 0;

    for (unsigned t = 0; t < SEQ; ++t) {
        // ---- xp from prefetched x_t (no serial load stall) ----
        float xp = bias;
#pragma unroll
        for (int k = 0; k < IND; ++k) xp += sat[k] * wih[k];

        // ---- issue x_{t+1} prefetch PRE-GATE: retires under gate+poll,
        //      leaves no vmem in flight at the barrier (R12's mistake) ----
        if (t + 1 < SEQ) {
            const float4* s4 = (const float4*)(sa + (size_t)(t + 1) * IND);
#pragma unroll
            for (int q = 0; q < 4; ++q) {
                float4 f = s4[q];
                sat[4 * q]     = f.x;
                sat[4 * q + 1] = f.y;
                sat[4 * q + 2] = f.z;
                sat[4 * q + 3] = f.w;
            }
        }

        // ---- clock gate: no LLC polls before own-publish + min flight ----
        if (t) {
            unsigned long long now;
            do {
                now = __builtin_amdgcn_s_memrealtime();
            } while (now - pubclk < GATE_TICKS);
        }

        // ---- poll own-XCD replica (sc1: memory-side, never stale) ----
        const unsigned pin = t & 1;
        const uint32_t* base =
            (const uint32_t*)(hrep + ((size_t)xcd * 2 + pin) * NSLOT);
        const uint32_t* pp0 = base + 4 * tid;
        const uint32_t* pp1 = base + 1024 + 4 * tid;
        u32x4 m0, m1;
        int tries = 0;
        for (;;) {
            asm volatile(
                "global_load_dwordx4 %0, %2, off sc1\n\t"
                "global_load_dwordx4 %1, %3, off sc1\n\t"
                "s_waitcnt vmcnt(0)"
                : "=v"(m0), "=v"(m1)
                : "v"(pp0), "v"(pp1) : "memory");
            bool ok = (m0.y == t) & (m0.w == t) & (m1.y == t) & (m1.w == t);
            if (ok) break;
            if (++tries > 2) __builtin_amdgcn_s_sleep(1);
        }

        // ---- stage 4 pairs into swizzled LDS (<=2-way = free) ----
        {
            paircvt cv;
            cv.u = m0.x; *wp0 = cv.v;
            cv.u = m0.z; *wp1 = cv.v;
            cv.u = m1.x; *wp2 = cv.v;
            cv.u = m1.z; *wp3 = cv.v;
        }
        __syncthreads();

        // ---- read this lane's 16 pairs (cols [32L, 32L+32)) ----
        h2 hv[16];
#pragma unroll
        for (int k = 0; k < 16; ++k)
            hv[k] = *rp[k];

        // ---- 8 rows x 32 cols of dot product per lane ----
        float p[8] = {0.f, 0.f, 0.f, 0.f, 0.f, 0.f, 0.f, 0.f};
#pragma unroll
        for (int r = 0; r < 8; ++r)
#pragma unroll
            for (int k = 0; k < 16; ++k)
                p[r] = fdot2f(wreg[r][k], hv[k], p[r]);

        // ---- merge-reduce: lane L ends with full sum of row (L&7) ----
        // xor1/xor2 stages on DPP (VALU), xor4/8 on DS, xor16/32 on
        // permlane swaps (VALU). Bit-identical arithmetic to R10.
        const bool h1 = (L & 1), h2b = (L & 2), h4 = (L & 4);
        float v0, v1, v2, v3;
        {
            float k0 = h1 ? p[1] : p[0], s0 = h1 ? p[0] : p[1];
            v0 = k0 + dpp_xor1(s0);
            float k1 = h1 ? p[3] : p[2], s1 = h1 ? p[2] : p[3];
            v1 = k1 + dpp_xor1(s1);
            float k2 = h1 ? p[5] : p[4], s2 = h1 ? p[4] : p[5];
            v2 = k2 + dpp_xor1(s2);
            float k3 = h1 ? p[7] : p[6], s3 = h1 ? p[6] : p[7];
            v3 = k3 + dpp_xor1(s3);
        }
        float w0, w1;
        {
            float k0 = h2b ? v1 : v0, s0 = h2b ? v0 : v1;
            w0 = k0 + dpp_xor2(s0);
            float k1 = h2b ? v3 : v2, s1 = h2b ? v2 : v3;
            w1 = k1 + dpp_xor2(s1);
        }
        float tot;
        {
            float k0 = h4 ? w1 : w0, s0 = h4 ? w0 : w1;
            tot = k0 + __shfl_xor(s0, 4, 64);
        }
        tot += __shfl_xor(tot, 8, 64);
        tot = xor16_add(tot);
        tot = xor32_add(tot);
        tot += xp;

        // ---- gates: all intra-wave (width-8 shuffles) ----
        const int ub4 = L & 4;   // 0 -> unit0 rows 0..3, 4 -> unit1 rows 4..7
        float gi = __shfl(tot, ub4 + 0, 8);
        float gf = __shfl(tot, ub4 + 1, 8);
        float gg = __shfl(tot, ub4 + 2, 8);
        float go = __shfl(tot, ub4 + 3, 8);
        float ii = sigmoid_f(gi);
        float ff = sigmoid_f(gf);
        float g  = tanh_f(gg);
        float oo = sigmoid_f(go);
        c = ff * c + ii * g;
        float h = oo * tanh_f(c);

        // ---- publish: two PARALLEL width-8 broadcasts, then lanes 0..7
        //      each store one replica (single predicated issue) ----
        {
            float hA = __shfl(h, 0, 8);   // unit ubase   (sublane 0)
            float hB = __shfl(h, 4, 8);   // unit ubase+1 (sublane 4)
            paircvt pk;
            pk.v.x = (_Float16)hA;
            pk.v.y = (_Float16)hB;
            const unsigned pout = (t + 1) & 1;
            const size_t slot = (size_t)b * 4 + w;
            unsigned long long msg =
                ((unsigned long long)(t + 1) << 32) | (unsigned long long)pk.u;
            if (L < 8)
                __hip_atomic_store(
                    &hrep[((size_t)L * 2 + pout) * NSLOT + slot], msg,
                    __ATOMIC_RELAXED, __HIP_MEMORY_SCOPE_AGENT);
            // non-critical history write, off the publishing lanes
            if (L == 8)
                ((unsigned*)hs16)[(size_t)t * (HD / 2) + b * 4 + w] = pk.u;
        }
        pubclk = __builtin_amdgcn_s_memrealtime();
    }
}

// Output projection: out[t,0:3] = hs[t]·W_uvw^T + b_uvw,
//                    out[t,3:6] = hs[t]·W_pqr^T + b_pqr
__global__ __launch_bounds__(256) void out_proj_kernel(
    const _Float16* __restrict__ hs16,
    const float* __restrict__ W_uvw, const float* __restrict__ b_uvw,
    const float* __restrict__ W_pqr, const float* __restrict__ b_pqr,
    float* __restrict__ out)
{
    __shared__ float Ws[6 * HD];
    const int tid = threadIdx.x;
    for (int i = tid; i < 3 * HD; i += 256) Ws[i] = W_uvw[i];
    for (int i = tid; i < 3 * HD; i += 256) Ws[3 * HD + i] = W_pqr[i];
    __syncthreads();

    const int w = tid >> 6, L = tid & 63;
#pragma unroll
    for (int r = 0; r < 4; ++r) {
        const int t = blockIdx.x * 16 + w * 4 + r;
        const _Float16* hrow = hs16 + (size_t)t * HD;
        float acc[6] = {0.f, 0.f, 0.f, 0.f, 0.f, 0.f};
        for (int cidx = L; cidx < HD; cidx += 64) {
            float hval = (float)hrow[cidx];
#pragma unroll
            for (int j = 0; j < 6; ++j) acc[j] += hval * Ws[j * HD + cidx];
        }
#pragma unroll
        for (int j = 0; j < 6; ++j) {
#pragma unroll
            for (int d = 1; d < 64; d <<= 1)
                acc[j] += __shfl_xor(acc[j], d, 64);
        }
        if (L == 0) {
#pragma unroll
            for (int j = 0; j < 6; ++j)
                out[(size_t)t * 6 + j] =
                    acc[j] + (j < 3 ? b_uvw[j] : b_pqr[j - 3]);
        }
    }
}

extern "C" void kernel_launch(void* const* d_in, const int* in_sizes, int n_in,
                              void* d_out, int out_size, void* d_ws, size_t ws_size,
                              hipStream_t stream) {
    (void)in_sizes; (void)n_in; (void)out_size; (void)ws_size;

    const float* sa    = (const float*)d_in[0];
    const float* W_ih  = (const float*)d_in[1];
    const float* W_hh  = (const float*)d_in[2];
    const float* b_ih  = (const float*)d_in[3];
    const float* b_hh  = (const float*)d_in[4];
    const float* W_uvw = (const float*)d_in[5];
    const float* b_uvw = (const float*)d_in[6];
    const float* W_pqr = (const float*)d_in[7];
    const float* b_pqr = (const float*)d_in[8];
    float* out = (float*)d_out;

    // workspace: [hs16: 32 MB][hrep: NXCD*2*NSLOT*8 = 128 KB]
    char* ws = (char*)d_ws;
    _Float16* hs16 = (_Float16*)ws;
    unsigned long long* hrep =
        (unsigned long long*)(ws + (size_t)SEQ * HD * 2);

    // zero replicas: tag 0 == "h_0 = 0 is ready" in every copy
    hipMemsetAsync(hrep, 0, (size_t)NXCD * 2 * NSLOT * 8, stream);

    hipLaunchKernelGGL(lstm_persist, dim3(NBLK), dim3(NTHR), 0, stream,
                       sa, W_ih, W_hh, b_ih, b_hh, hrep, hs16);
    hipLaunchKernelGGL(out_proj_kernel, dim3(SEQ / 16), dim3(256), 0, stream,
                       hs16, W_uvw, b_uvw, W_pqr, b_pqr, out);
}

// Round 5
// 14307.375 us; speedup vs baseline: 1.3985x; 1.0022x over previous
//
#include <hip/hip_runtime.h>
#include <cstdint>
#include <cstddef>

#define SEQ   8192
#define HD    2048
#define IND   16
#define NBLK  256   // one block per CU; each owns 8 hidden units
#define NTHR  256   // 4 waves; wave w owns units {b*8+2w, b*8+2w+1} = 8 rows
#define NSLOT 1024  // u64 slots per parity: lo32 = 2xfp16 h-pair, hi32 = tag
#define NXCD  8

// Poll gate, R14 calibration: R13 used 14 ticks (~340cy) and the first
// poll round sampled the LLC at ~640cy after own publish -- often BEFORE
// store visibility (~700-900cy incl. producer jitter), wasting a full
// ~650cy round on most steps. 24 ticks (~576cy) puts round-1's sample at
// ~850-900cy: common-case discovery on the FIRST round. Still referenced
// to OWN publish (every peer waits on our slots too) -> ratchet-safe;
// overshoot risk bounded at ~(576 - T_vis) cy and revertible.
#define GATE_TICKS 24ull
// Tight re-polls before s_sleep backoff: gate already prevents early
// hammering, so post-gate data is imminent; tight rounds cut discovery
// staleness and remove the 64cy sleep-quantum jitter from the per-step
// max-over-256-blocks straggler term.
#define TIGHT_TRIES 4

typedef _Float16 h2  __attribute__((ext_vector_type(2)));
typedef unsigned u32x4 __attribute__((ext_vector_type(4)));

union paircvt { h2 v; unsigned u; };

__device__ __forceinline__ float fdot2f(h2 a, h2 b, float c) {
#if defined(__has_builtin)
#if __has_builtin(__builtin_amdgcn_fdot2)
    return __builtin_amdgcn_fdot2(a, b, c, false);
#else
    return c + (float)a.x * (float)b.x + (float)a.y * (float)b.y;
#endif
#else
    return c + (float)a.x * (float)b.x + (float)a.y * (float)b.y;
#endif
}

__device__ __forceinline__ float sigmoid_f(float x) {
    return 1.f / (1.f + __expf(-x));
}
__device__ __forceinline__ float tanh_f(float x) {
    float e = __expf(2.f * x);
    return 1.f - 2.f / (e + 1.f);
}

__device__ __forceinline__ unsigned my_xcd() {
    unsigned x;
    asm volatile("s_getreg_b32 %0, hwreg(HW_REG_XCC_ID, 0, 4)" : "=s"(x));
    return x & (NXCD - 1);
}

// ---- VALU cross-lane primitives (replace DS-pipe shuffles) ----
// xor-1 / xor-2 are exact DPP quad_perm patterns: ~8cy VALU vs ~40cy DS.
__device__ __forceinline__ float dpp_xor1(float x) {
    int i = __builtin_bit_cast(int, x);
    // quad_perm [1,0,3,2] = 0xB1 : lane L reads L^1
    int r = __builtin_amdgcn_mov_dpp(i, 0xB1, 0xf, 0xf, false);
    return __builtin_bit_cast(float, r);
}
__device__ __forceinline__ float dpp_xor2(float x) {
    int i = __builtin_bit_cast(int, x);
    // quad_perm [2,3,0,1] = 0x4E : lane L reads L^2
    int r = __builtin_amdgcn_mov_dpp(i, 0x4E, 0xf, 0xf, false);
    return __builtin_bit_cast(float, r);
}
// gfx950 permlane swaps: copy+swap+add = xor-16 / xor-32 butterfly stage,
// bit-identical result (commutative add), VALU-pipe instead of DS-pipe.
__device__ __forceinline__ float xor16_add(float x) {
    float a = x, b = x;
    asm volatile("v_permlane16_swap_b32 %0, %1" : "+v"(a), "+v"(b));
    return a + b;
}
__device__ __forceinline__ float xor32_add(float x) {
    float a = x, b = x;
    asm volatile("v_permlane32_swap_b32 %0, %1" : "+v"(a), "+v"(b));
    return a + b;
}

// Persistent LSTM, round 14: discovery-timing calibration on top of R13
// (14.34ms). R13 = proven structure: pre-gate sat prefetch (nothing in
// vmem flight at barrier), DPP/permlane reduce, hoisted LDS swizzle
// addresses, parallel width-8 publish broadcasts, lane-spread replica
// stores. R14 changes ONLY the two discovery constants (GATE_TICKS 14->24,
// tight tries 2->4); everything else is byte-identical to R13.
__global__ __launch_bounds__(NTHR, 1) void lstm_persist(
    const float* __restrict__ sa,    // [SEQ, IND]
    const float* __restrict__ W_ih,  // [4*HD, IND]
    const float* __restrict__ W_hh,  // [4*HD, HD]
    const float* __restrict__ b_ih,  // [4*HD]
    const float* __restrict__ b_hh,  // [4*HD]
    unsigned long long* __restrict__ hrep,  // [NXCD][2][NSLOT] replicas
    _Float16* __restrict__ hs16)     // [SEQ, HD] h history (fp16)
{
    const int b   = blockIdx.x;
    const int tid = threadIdx.x;
    const int w   = tid >> 6;        // wave 0..3
    const int L   = tid & 63;        // lane
    const unsigned xcd = my_xcd();

    __shared__ h2 hh2[16 * 64];      // h_t pairs, XOR-swizzled [k][row^2k]

    const int ubase = b * 8 + 2 * w; // first of this wave's 2 units

    // ---- one-time: W_hh fragment -> registers (fp16 pairs) ----
    // 8 rows (r: gate=r&3, unit=r>>2), lane L owns cols [32L, 32L+32)
    h2 wreg[8][16];
#pragma unroll
    for (int r = 0; r < 8; ++r) {
        const int row = (r & 3) * HD + ubase + (r >> 2);
        const float4* Wr = (const float4*)(W_hh + (size_t)row * HD + L * 32);
#pragma unroll
        for (int q = 0; q < 8; ++q) {
            float4 f = Wr[q];
            h2 lo; lo.x = (_Float16)f.x; lo.y = (_Float16)f.y;
            h2 hi; hi.x = (_Float16)f.z; hi.y = (_Float16)f.w;
            wreg[r][2 * q]     = lo;
            wreg[r][2 * q + 1] = hi;
        }
    }
    // W_ih row + bias for the row this lane ends up holding (r = L&7)
    const int rowL = (L & 3) * HD + ubase + ((L >> 2) & 1);
    float wih[IND];
    {
        const float4* Wi = (const float4*)(W_ih + (size_t)rowL * IND);
#pragma unroll
        for (int q = 0; q < 4; ++q) {
            float4 f = Wi[q];
            wih[4 * q]     = f.x;
            wih[4 * q + 1] = f.y;
            wih[4 * q + 2] = f.z;
            wih[4 * q + 3] = f.w;
        }
    }
    const float bias = b_ih[rowL] + b_hh[rowL];

    // ---- hoisted LDS addresses (loop-invariant swizzle math) ----
    h2* wp0; h2* wp1; h2* wp2; h2* wp3;
    {
        const int pa = 2 * tid, pb = 2 * tid + 1;
        const int pc = 512 + 2 * tid, pd = 513 + 2 * tid;
        wp0 = &hh2[(pa & 15) * 64 + (((pa >> 4) ^ (2 * (pa & 15))) & 63)];
        wp1 = &hh2[(pb & 15) * 64 + (((pb >> 4) ^ (2 * (pb & 15))) & 63)];
        wp2 = &hh2[(pc & 15) * 64 + (((pc >> 4) ^ (2 * (pc & 15))) & 63)];
        wp3 = &hh2[(pd & 15) * 64 + (((pd >> 4) ^ (2 * (pd & 15))) & 63)];
    }
    const h2* rp[16];
#pragma unroll
    for (int k = 0; k < 16; ++k)
        rp[k] = &hh2[k * 64 + ((L ^ (2 * k)) & 63)];

    // x_t prefetch registers (depth 1)
    float sat[IND];
    {
        const float4* s4 = (const float4*)(sa);
#pragma unroll
        for (int q = 0; q < 4; ++q) {
            float4 f = s4[q];
            sat[4 * q]     = f.x;
            sat[4 * q + 1] = f.y;
            sat[4 * q + 2] = f.z;
            sat[4 * q + 3] = f.w;
        }
    }

    // cell state: lanes with (L&4)==0 hold c of unit0, (L&4)==4 -> unit1
    float c = 0.f;
    unsigned long long pubclk = 0;

    for (unsigned t = 0; t < SEQ; ++t) {
        // ---- xp from prefetched x_t (no serial load stall) ----
        float xp = bias;
#pragma unroll
        for (int k = 0; k < IND; ++k) xp += sat[k] * wih[k];

        // ---- issue x_{t+1} prefetch PRE-GATE: retires under gate+poll,
        //      leaves no vmem in flight at the barrier ----
        if (t + 1 < SEQ) {
            const float4* s4 = (const float4*)(sa + (size_t)(t + 1) * IND);
#pragma unroll
            for (int q = 0; q < 4; ++q) {
                float4 f = s4[q];
                sat[4 * q]     = f.x;
                sat[4 * q + 1] = f.y;
                sat[4 * q + 2] = f.z;
                sat[4 * q + 3] = f.w;
            }
        }

        // ---- clock gate: no LLC polls before own-publish + T_vis est. ----
        if (t) {
            unsigned long long now;
            do {
                now = __builtin_amdgcn_s_memrealtime();
            } while (now - pubclk < GATE_TICKS);
        }

        // ---- poll own-XCD replica (sc1: memory-side, never stale) ----
        const unsigned pin = t & 1;
        const uint32_t* base =
            (const uint32_t*)(hrep + ((size_t)xcd * 2 + pin) * NSLOT);
        const uint32_t* pp0 = base + 4 * tid;
        const uint32_t* pp1 = base + 1024 + 4 * tid;
        u32x4 m0, m1;
        int tries = 0;
        for (;;) {
            asm volatile(
                "global_load_dwordx4 %0, %2, off sc1\n\t"
                "global_load_dwordx4 %1, %3, off sc1\n\t"
                "s_waitcnt vmcnt(0)"
                : "=v"(m0), "=v"(m1)
                : "v"(pp0), "v"(pp1) : "memory");
            bool ok = (m0.y == t) & (m0.w == t) & (m1.y == t) & (m1.w == t);
            if (ok) break;
            if (++tries > TIGHT_TRIES) __builtin_amdgcn_s_sleep(1);
        }

        // ---- stage 4 pairs into swizzled LDS (<=2-way = free) ----
        {
            paircvt cv;
            cv.u = m0.x; *wp0 = cv.v;
            cv.u = m0.z; *wp1 = cv.v;
            cv.u = m1.x; *wp2 = cv.v;
            cv.u = m1.z; *wp3 = cv.v;
        }
        __syncthreads();

        // ---- read this lane's 16 pairs (cols [32L, 32L+32)) ----
        h2 hv[16];
#pragma unroll
        for (int k = 0; k < 16; ++k)
            hv[k] = *rp[k];

        // ---- 8 rows x 32 cols of dot product per lane ----
        float p[8] = {0.f, 0.f, 0.f, 0.f, 0.f, 0.f, 0.f, 0.f};
#pragma unroll
        for (int r = 0; r < 8; ++r)
#pragma unroll
            for (int k = 0; k < 16; ++k)
                p[r] = fdot2f(wreg[r][k], hv[k], p[r]);

        // ---- merge-reduce: lane L ends with full sum of row (L&7) ----
        // xor1/xor2 stages on DPP (VALU), xor4/8 on DS, xor16/32 on
        // permlane swaps (VALU). Bit-identical arithmetic to R10.
        const bool h1 = (L & 1), h2b = (L & 2), h4 = (L & 4);
        float v0, v1, v2, v3;
        {
            float k0 = h1 ? p[1] : p[0], s0 = h1 ? p[0] : p[1];
            v0 = k0 + dpp_xor1(s0);
            float k1 = h1 ? p[3] : p[2], s1 = h1 ? p[2] : p[3];
            v1 = k1 + dpp_xor1(s1);
            float k2 = h1 ? p[5] : p[4], s2 = h1 ? p[4] : p[5];
            v2 = k2 + dpp_xor1(s2);
            float k3 = h1 ? p[7] : p[6], s3 = h1 ? p[6] : p[7];
            v3 = k3 + dpp_xor1(s3);
        }
        float w0, w1;
        {
            float k0 = h2b ? v1 : v0, s0 = h2b ? v0 : v1;
            w0 = k0 + dpp_xor2(s0);
            float k1 = h2b ? v3 : v2, s1 = h2b ? v2 : v3;
            w1 = k1 + dpp_xor2(s1);
        }
        float tot;
        {
            float k0 = h4 ? w1 : w0, s0 = h4 ? w0 : w1;
            tot = k0 + __shfl_xor(s0, 4, 64);
        }
        tot += __shfl_xor(tot, 8, 64);
        tot = xor16_add(tot);
        tot = xor32_add(tot);
        tot += xp;

        // ---- gates: all intra-wave (width-8 shuffles) ----
        const int ub4 = L & 4;   // 0 -> unit0 rows 0..3, 4 -> unit1 rows 4..7
        float gi = __shfl(tot, ub4 + 0, 8);
        float gf = __shfl(tot, ub4 + 1, 8);
        float gg = __shfl(tot, ub4 + 2, 8);
        float go = __shfl(tot, ub4 + 3, 8);
        float ii = sigmoid_f(gi);
        float ff = sigmoid_f(gf);
        float g  = tanh_f(gg);
        float oo = sigmoid_f(go);
        c = ff * c + ii * g;
        float h = oo * tanh_f(c);

        // ---- publish: two PARALLEL width-8 broadcasts, then lanes 0..7
        //      each store one replica (single predicated issue) ----
        {
            float hA = __shfl(h, 0, 8);   // unit ubase   (sublane 0)
            float hB = __shfl(h, 4, 8);   // unit ubase+1 (sublane 4)
            paircvt pk;
            pk.v.x = (_Float16)hA;
            pk.v.y = (_Float16)hB;
            const unsigned pout = (t + 1) & 1;
            const size_t slot = (size_t)b * 4 + w;
            unsigned long long msg =
                ((unsigned long long)(t + 1) << 32) | (unsigned long long)pk.u;
            if (L < 8)
                __hip_atomic_store(
                    &hrep[((size_t)L * 2 + pout) * NSLOT + slot], msg,
                    __ATOMIC_RELAXED, __HIP_MEMORY_SCOPE_AGENT);
            // non-critical history write, off the publishing lanes
            if (L == 8)
                ((unsigned*)hs16)[(size_t)t * (HD / 2) + b * 4 + w] = pk.u;
        }
        pubclk = __builtin_amdgcn_s_memrealtime();
    }
}

// Output projection: out[t,0:3] = hs[t]·W_uvw^T + b_uvw,
//                    out[t,3:6] = hs[t]·W_pqr^T + b_pqr
__global__ __launch_bounds__(256) void out_proj_kernel(
    const _Float16* __restrict__ hs16,
    const float* __restrict__ W_uvw, const float* __restrict__ b_uvw,
    const float* __restrict__ W_pqr, const float* __restrict__ b_pqr,
    float* __restrict__ out)
{
    __shared__ float Ws[6 * HD];
    const int tid = threadIdx.x;
    for (int i = tid; i < 3 * HD; i += 256) Ws[i] = W_uvw[i];
    for (int i = tid; i < 3 * HD; i += 256) Ws[3 * HD + i] = W_pqr[i];
    __syncthreads();

    const int w = tid >> 6, L = tid & 63;
#pragma unroll
    for (int r = 0; r < 4; ++r) {
        const int t = blockIdx.x * 16 + w * 4 + r;
        const _Float16* hrow = hs16 + (size_t)t * HD;
        float acc[6] = {0.f, 0.f, 0.f, 0.f, 0.f, 0.f};
        for (int cidx = L; cidx < HD; cidx += 64) {
            float hval = (float)hrow[cidx];
#pragma unroll
            for (int j = 0; j < 6; ++j) acc[j] += hval * Ws[j * HD + cidx];
        }
#pragma unroll
        for (int j = 0; j < 6; ++j) {
#pragma unroll
            for (int d = 1; d < 64; d <<= 1)
                acc[j] += __shfl_xor(acc[j], d, 64);
        }
        if (L == 0) {
#pragma unroll
            for (int j = 0; j < 6; ++j)
                out[(size_t)t * 6 + j] =
                    acc[j] + (j < 3 ? b_uvw[j] : b_pqr[j - 3]);
        }
    }
}

extern "C" void kernel_launch(void* const* d_in, const int* in_sizes, int n_in,
                              void* d_out, int out_size, void* d_ws, size_t ws_size,
                              hipStream_t stream) {
    (void)in_sizes; (void)n_in; (void)out_size; (void)ws_size;

    const float* sa    = (const float*)d_in[0];
    const float* W_ih  = (const float*)d_in[1];
    const float* W_hh  = (const float*)d_in[2];
    const float* b_ih  = (const float*)d_in[3];
    const float* b_hh  = (const float*)d_in[4];
    const float* W_uvw = (const float*)d_in[5];
    const float* b_uvw = (const float*)d_in[6];
    const float* W_pqr = (const float*)d_in[7];
    const float* b_pqr = (const float*)d_in[8];
    float* out = (float*)d_out;

    // workspace: [hs16: 32 MB][hrep: NXCD*2*NSLOT*8 = 128 KB]
    char* ws = (char*)d_ws;
    _Float16* hs16 = (_Float16*)ws;
    unsigned long long* hrep =
        (unsigned long long*)(ws + (size_t)SEQ * HD * 2);

    // zero replicas: tag 0 == "h_0 = 0 is ready" in every copy
    hipMemsetAsync(hrep, 0, (size_t)NXCD * 2 * NSLOT * 8, stream);

    hipLaunchKernelGGL(lstm_persist, dim3(NBLK), dim3(NTHR), 0, stream,
                       sa, W_ih, W_hh, b_ih, b_hh, hrep, hs16);
    hipLaunchKernelGGL(out_proj_kernel, dim3(SEQ / 16), dim3(256), 0, stream,
                       hs16, W_uvw, b_uvw, W_pqr, b_pqr, out);
}

// Round 6
// 14100.160 us; speedup vs baseline: 1.4190x; 1.0147x over previous
//
#include <hip/hip_runtime.h>
#include <cstdint>
#include <cstddef>

#define SEQ   8192
#define HD    2048
#define IND   16
#define NBLK  256   // one block per CU; each owns 8 hidden units
#define NTHR  256   // 4 waves; wave w owns units {b*8+2w, b*8+2w+1} = 8 rows
#define NSLOT 1024  // u64 slots per parity: lo32 = 2xfp16 h-pair, hi32 = tag
#define NXCD  8

// Poll gate: R14 showed 14 vs 24 ticks is NEUTRAL -> T_vis ~ 850-1300cy and
// discovery lands round 1-2 either way; the cost is round-trip QUANTIZATION
// (~600cy), not gate placement. R15 polls with a staggered double-buffer
// (samples every ~300cy), so start early: 16 ticks (~384cy).
#define GATE_TICKS 16ull

typedef _Float16 h2  __attribute__((ext_vector_type(2)));
typedef unsigned u32x4 __attribute__((ext_vector_type(4)));

union paircvt { h2 v; unsigned u; };

__device__ __forceinline__ float fdot2f(h2 a, h2 b, float c) {
#if defined(__has_builtin)
#if __has_builtin(__builtin_amdgcn_fdot2)
    return __builtin_amdgcn_fdot2(a, b, c, false);
#else
    return c + (float)a.x * (float)b.x + (float)a.y * (float)b.y;
#endif
#else
    return c + (float)a.x * (float)b.x + (float)a.y * (float)b.y;
#endif
}

__device__ __forceinline__ float sigmoid_f(float x) {
    return 1.f / (1.f + __expf(-x));
}
__device__ __forceinline__ float tanh_f(float x) {
    float e = __expf(2.f * x);
    return 1.f - 2.f / (e + 1.f);
}

__device__ __forceinline__ unsigned my_xcd() {
    unsigned x;
    asm volatile("s_getreg_b32 %0, hwreg(HW_REG_XCC_ID, 0, 4)" : "=s"(x));
    return x & (NXCD - 1);
}

// ---- VALU cross-lane primitives (replace DS-pipe shuffles) ----
__device__ __forceinline__ float dpp_xor1(float x) {
    int i = __builtin_bit_cast(int, x);
    int r = __builtin_amdgcn_mov_dpp(i, 0xB1, 0xf, 0xf, false); // [1,0,3,2]
    return __builtin_bit_cast(float, r);
}
__device__ __forceinline__ float dpp_xor2(float x) {
    int i = __builtin_bit_cast(int, x);
    int r = __builtin_amdgcn_mov_dpp(i, 0x4E, 0xf, 0xf, false); // [2,3,0,1]
    return __builtin_bit_cast(float, r);
}
__device__ __forceinline__ float xor16_add(float x) {
    float a = x, b = x;
    asm volatile("v_permlane16_swap_b32 %0, %1" : "+v"(a), "+v"(b));
    return a + b;
}
__device__ __forceinline__ float xor32_add(float x) {
    float a = x, b = x;
    asm volatile("v_permlane32_swap_b32 %0, %1" : "+v"(a), "+v"(b));
    return a + b;
}

// Persistent LSTM, round 15: staggered double-buffered poll + raw barrier.
// R14 neutral-gate post-mortem: discovery cost is the ~600cy poll round
// QUANTIZATION (avg ~300cy staleness at success) + its jitter feeding the
// 256-block straggler max. Changes vs R14 (compute path byte-identical):
//  (1) poll keeps TWO load-pairs in flight, staggered ~half a round trip:
//      a fresh sample every ~300cy instead of ~600cy.
//  (2) success exits with 2 stale loads in flight. __syncthreads() would
//      drain them (s_waitcnt vmcnt(0) before s_barrier -- R12's failure
//      mode). Replaced with s_waitcnt lgkmcnt(0) + RAW s_barrier: only the
//      LDS staging writes are ordered; stale poll loads retire under the
//      dot phase and are gone by next step's pre-poll vmcnt(0).
//  (3) gate 24 -> 16 ticks (start sampling earlier; stagger covers T_vis).
__global__ __launch_bounds__(NTHR, 1) void lstm_persist(
    const float* __restrict__ sa,    // [SEQ, IND]
    const float* __restrict__ W_ih,  // [4*HD, IND]
    const float* __restrict__ W_hh,  // [4*HD, HD]
    const float* __restrict__ b_ih,  // [4*HD]
    const float* __restrict__ b_hh,  // [4*HD]
    unsigned long long* __restrict__ hrep,  // [NXCD][2][NSLOT] replicas
    _Float16* __restrict__ hs16)     // [SEQ, HD] h history (fp16)
{
    const int b   = blockIdx.x;
    const int tid = threadIdx.x;
    const int w   = tid >> 6;        // wave 0..3
    const int L   = tid & 63;        // lane
    const unsigned xcd = my_xcd();

    __shared__ h2 hh2[16 * 64];      // h_t pairs, XOR-swizzled [k][row^2k]

    const int ubase = b * 8 + 2 * w; // first of this wave's 2 units

    // ---- one-time: W_hh fragment -> registers (fp16 pairs) ----
    h2 wreg[8][16];
#pragma unroll
    for (int r = 0; r < 8; ++r) {
        const int row = (r & 3) * HD + ubase + (r >> 2);
        const float4* Wr = (const float4*)(W_hh + (size_t)row * HD + L * 32);
#pragma unroll
        for (int q = 0; q < 8; ++q) {
            float4 f = Wr[q];
            h2 lo; lo.x = (_Float16)f.x; lo.y = (_Float16)f.y;
            h2 hi; hi.x = (_Float16)f.z; hi.y = (_Float16)f.w;
            wreg[r][2 * q]     = lo;
            wreg[r][2 * q + 1] = hi;
        }
    }
    // W_ih row + bias for the row this lane ends up holding (r = L&7)
    const int rowL = (L & 3) * HD + ubase + ((L >> 2) & 1);
    float wih[IND];
    {
        const float4* Wi = (const float4*)(W_ih + (size_t)rowL * IND);
#pragma unroll
        for (int q = 0; q < 4; ++q) {
            float4 f = Wi[q];
            wih[4 * q]     = f.x;
            wih[4 * q + 1] = f.y;
            wih[4 * q + 2] = f.z;
            wih[4 * q + 3] = f.w;
        }
    }
    const float bias = b_ih[rowL] + b_hh[rowL];

    // ---- hoisted LDS addresses (loop-invariant swizzle math) ----
    h2* wp0; h2* wp1; h2* wp2; h2* wp3;
    {
        const int pa = 2 * tid, pb = 2 * tid + 1;
        const int pc = 512 + 2 * tid, pd = 513 + 2 * tid;
        wp0 = &hh2[(pa & 15) * 64 + (((pa >> 4) ^ (2 * (pa & 15))) & 63)];
        wp1 = &hh2[(pb & 15) * 64 + (((pb >> 4) ^ (2 * (pb & 15))) & 63)];
        wp2 = &hh2[(pc & 15) * 64 + (((pc >> 4) ^ (2 * (pc & 15))) & 63)];
        wp3 = &hh2[(pd & 15) * 64 + (((pd >> 4) ^ (2 * (pd & 15))) & 63)];
    }
    const h2* rp[16];
#pragma unroll
    for (int k = 0; k < 16; ++k)
        rp[k] = &hh2[k * 64 + ((L ^ (2 * k)) & 63)];

    // x_t prefetch registers (depth 1)
    float sat[IND];
    {
        const float4* s4 = (const float4*)(sa);
#pragma unroll
        for (int q = 0; q < 4; ++q) {
            float4 f = s4[q];
            sat[4 * q]     = f.x;
            sat[4 * q + 1] = f.y;
            sat[4 * q + 2] = f.z;
            sat[4 * q + 3] = f.w;
        }
    }

    // cell state: lanes with (L&4)==0 hold c of unit0, (L&4)==4 -> unit1
    float c = 0.f;
    unsigned long long pubclk = 0;

    for (unsigned t = 0; t < SEQ; ++t) {
        // ---- xp from prefetched x_t (no serial load stall) ----
        float xp = bias;
#pragma unroll
        for (int k = 0; k < IND; ++k) xp += sat[k] * wih[k];

        // ---- issue x_{t+1} prefetch PRE-GATE: retires under gate+poll ----
        if (t + 1 < SEQ) {
            const float4* s4 = (const float4*)(sa + (size_t)(t + 1) * IND);
#pragma unroll
            for (int q = 0; q < 4; ++q) {
                float4 f = s4[q];
                sat[4 * q]     = f.x;
                sat[4 * q + 1] = f.y;
                sat[4 * q + 2] = f.z;
                sat[4 * q + 3] = f.w;
            }
        }

        // ---- clock gate: no LLC polls before own-publish + min flight ----
        if (t) {
            unsigned long long now;
            do {
                now = __builtin_amdgcn_s_memrealtime();
            } while (now - pubclk < GATE_TICKS);
        }

        // ---- staggered double-buffered poll of own-XCD replica ----
        const unsigned pin = t & 1;
        const uint32_t* base =
            (const uint32_t*)(hrep + ((size_t)xcd * 2 + pin) * NSLOT);
        const uint32_t* pp0 = base + 4 * tid;
        const uint32_t* pp1 = base + 1024 + 4 * tid;
        u32x4 m0, m1, n0, n1;
        // drain prior vmem (sat prefetch + last step's stale polls: retired
        // long ago under gate/compute -> free)
        asm volatile("s_waitcnt vmcnt(0)" ::: "memory");
        // issue sample A
        asm volatile(
            "global_load_dwordx4 %0, %2, off sc1\n\t"
            "global_load_dwordx4 %1, %3, off sc1"
            : "=v"(m0), "=v"(m1) : "v"(pp0), "v"(pp1) : "memory");
        int tries = 0;
        for (;;) {
            // issue sample B (A still in flight -> staggered)
            asm volatile(
                "global_load_dwordx4 %0, %2, off sc1\n\t"
                "global_load_dwordx4 %1, %3, off sc1"
                : "=v"(n0), "=v"(n1) : "v"(pp0), "v"(pp1) : "memory");
            // wait for A only (2 newer ops outstanding)
            asm volatile("s_waitcnt vmcnt(2)"
                         : "+v"(m0), "+v"(m1) :: "memory");
            if ((m0.y == t) & (m0.w == t) & (m1.y == t) & (m1.w == t))
                break;                       // B stays in flight (harmless)
            // re-issue sample A
            asm volatile(
                "global_load_dwordx4 %0, %2, off sc1\n\t"
                "global_load_dwordx4 %1, %3, off sc1"
                : "=v"(m0), "=v"(m1) : "v"(pp0), "v"(pp1) : "memory");
            // wait for B only
            asm volatile("s_waitcnt vmcnt(2)"
                         : "+v"(n0), "+v"(n1) :: "memory");
            if ((n0.y == t) & (n0.w == t) & (n1.y == t) & (n1.w == t)) {
                m0 = n0; m1 = n1;            // A' stays in flight (harmless)
                break;
            }
            if (++tries > 8) __builtin_amdgcn_s_sleep(1);
        }

        // ---- stage 4 pairs into swizzled LDS (<=2-way = free) ----
        {
            paircvt cv;
            cv.u = m0.x; *wp0 = cv.v;
            cv.u = m0.z; *wp1 = cv.v;
            cv.u = m1.x; *wp2 = cv.v;
            cv.u = m1.z; *wp3 = cv.v;
        }
        // RAW barrier: order only the LDS staging (lgkmcnt), NOT vmcnt --
        // stale staggered poll loads may cross and retire under the dots.
        asm volatile("s_waitcnt lgkmcnt(0)" ::: "memory");
        __builtin_amdgcn_s_barrier();

        // ---- read this lane's 16 pairs (cols [32L, 32L+32)) ----
        h2 hv[16];
#pragma unroll
        for (int k = 0; k < 16; ++k)
            hv[k] = *rp[k];

        // ---- 8 rows x 32 cols of dot product per lane ----
        float p[8] = {0.f, 0.f, 0.f, 0.f, 0.f, 0.f, 0.f, 0.f};
#pragma unroll
        for (int r = 0; r < 8; ++r)
#pragma unroll
            for (int k = 0; k < 16; ++k)
                p[r] = fdot2f(wreg[r][k], hv[k], p[r]);

        // ---- merge-reduce: lane L ends with full sum of row (L&7) ----
        const bool h1 = (L & 1), h2b = (L & 2), h4 = (L & 4);
        float v0, v1, v2, v3;
        {
            float k0 = h1 ? p[1] : p[0], s0 = h1 ? p[0] : p[1];
            v0 = k0 + dpp_xor1(s0);
            float k1 = h1 ? p[3] : p[2], s1 = h1 ? p[2] : p[3];
            v1 = k1 + dpp_xor1(s1);
            float k2 = h1 ? p[5] : p[4], s2 = h1 ? p[4] : p[5];
            v2 = k2 + dpp_xor1(s2);
            float k3 = h1 ? p[7] : p[6], s3 = h1 ? p[6] : p[7];
            v3 = k3 + dpp_xor1(s3);
        }
        float w0, w1;
        {
            float k0 = h2b ? v1 : v0, s0 = h2b ? v0 : v1;
            w0 = k0 + dpp_xor2(s0);
            float k1 = h2b ? v3 : v2, s1 = h2b ? v2 : v3;
            w1 = k1 + dpp_xor2(s1);
        }
        float tot;
        {
            float k0 = h4 ? w1 : w0, s0 = h4 ? w0 : w1;
            tot = k0 + __shfl_xor(s0, 4, 64);
        }
        tot += __shfl_xor(tot, 8, 64);
        tot = xor16_add(tot);
        tot = xor32_add(tot);
        tot += xp;

        // ---- gates: all intra-wave (width-8 shuffles) ----
        const int ub4 = L & 4;   // 0 -> unit0 rows 0..3, 4 -> unit1 rows 4..7
        float gi = __shfl(tot, ub4 + 0, 8);
        float gf = __shfl(tot, ub4 + 1, 8);
        float gg = __shfl(tot, ub4 + 2, 8);
        float go = __shfl(tot, ub4 + 3, 8);
        float ii = sigmoid_f(gi);
        float ff = sigmoid_f(gf);
        float g  = tanh_f(gg);
        float oo = sigmoid_f(go);
        c = ff * c + ii * g;
        float h = oo * tanh_f(c);

        // ---- publish: two PARALLEL width-8 broadcasts, then lanes 0..7
        //      each store one replica (single predicated issue) ----
        {
            float hA = __shfl(h, 0, 8);   // unit ubase   (sublane 0)
            float hB = __shfl(h, 4, 8);   // unit ubase+1 (sublane 4)
            paircvt pk;
            pk.v.x = (_Float16)hA;
            pk.v.y = (_Float16)hB;
            const unsigned pout = (t + 1) & 1;
            const size_t slot = (size_t)b * 4 + w;
            unsigned long long msg =
                ((unsigned long long)(t + 1) << 32) | (unsigned long long)pk.u;
            if (L < 8)
                __hip_atomic_store(
                    &hrep[((size_t)L * 2 + pout) * NSLOT + slot], msg,
                    __ATOMIC_RELAXED, __HIP_MEMORY_SCOPE_AGENT);
            // non-critical history write, off the publishing lanes
            if (L == 8)
                ((unsigned*)hs16)[(size_t)t * (HD / 2) + b * 4 + w] = pk.u;
        }
        pubclk = __builtin_amdgcn_s_memrealtime();
    }
}

// Output projection: out[t,0:3] = hs[t]·W_uvw^T + b_uvw,
//                    out[t,3:6] = hs[t]·W_pqr^T + b_pqr
__global__ __launch_bounds__(256) void out_proj_kernel(
    const _Float16* __restrict__ hs16,
    const float* __restrict__ W_uvw, const float* __restrict__ b_uvw,
    const float* __restrict__ W_pqr, const float* __restrict__ b_pqr,
    float* __restrict__ out)
{
    __shared__ float Ws[6 * HD];
    const int tid = threadIdx.x;
    for (int i = tid; i < 3 * HD; i += 256) Ws[i] = W_uvw[i];
    for (int i = tid; i < 3 * HD; i += 256) Ws[3 * HD + i] = W_pqr[i];
    __syncthreads();

    const int w = tid >> 6, L = tid & 63;
#pragma unroll
    for (int r = 0; r < 4; ++r) {
        const int t = blockIdx.x * 16 + w * 4 + r;
        const _Float16* hrow = hs16 + (size_t)t * HD;
        float acc[6] = {0.f, 0.f, 0.f, 0.f, 0.f, 0.f};
        for (int cidx = L; cidx < HD; cidx += 64) {
            float hval = (float)hrow[cidx];
#pragma unroll
            for (int j = 0; j < 6; ++j) acc[j] += hval * Ws[j * HD + cidx];
        }
#pragma unroll
        for (int j = 0; j < 6; ++j) {
#pragma unroll
            for (int d = 1; d < 64; d <<= 1)
                acc[j] += __shfl_xor(acc[j], d, 64);
        }
        if (L == 0) {
#pragma unroll
            for (int j = 0; j < 6; ++j)
                out[(size_t)t * 6 + j] =
                    acc[j] + (j < 3 ? b_uvw[j] : b_pqr[j - 3]);
        }
    }
}

extern "C" void kernel_launch(void* const* d_in, const int* in_sizes, int n_in,
                              void* d_out, int out_size, void* d_ws, size_t ws_size,
                              hipStream_t stream) {
    (void)in_sizes; (void)n_in; (void)out_size; (void)ws_size;

    const float* sa    = (const float*)d_in[0];
    const float* W_ih  = (const float*)d_in[1];
    const float* W_hh  = (const float*)d_in[2];
    const float* b_ih  = (const float*)d_in[3];
    const float* b_hh  = (const float*)d_in[4];
    const float* W_uvw = (const float*)d_in[5];
    const float* b_uvw = (const float*)d_in[6];
    const float* W_pqr = (const float*)d_in[7];
    const float* b_pqr = (const float*)d_in[8];
    float* out = (float*)d_out;

    // workspace: [hs16: 32 MB][hrep: NXCD*2*NSLOT*8 = 128 KB]
    char* ws = (char*)d_ws;
    _Float16* hs16 = (_Float16*)ws;
    unsigned long long* hrep =
        (unsigned long long*)(ws + (size_t)SEQ * HD * 2);

    // zero replicas: tag 0 == "h_0 = 0 is ready" in every copy
    hipMemsetAsync(hrep, 0, (size_t)NXCD * 2 * NSLOT * 8, stream);

    hipLaunchKernelGGL(lstm_persist, dim3(NBLK), dim3(NTHR), 0, stream,
                       sa, W_ih, W_hh, b_ih, b_hh, hrep, hs16);
    hipLaunchKernelGGL(out_proj_kernel, dim3(SEQ / 16), dim3(256), 0, stream,
                       hs16, W_uvw, b_uvw, W_pqr, b_pqr, out);
}